// Round 17
// baseline (132.060 us; speedup 1.0000x reference)
//
#include <hip/hip_runtime.h>
#include <hip/hip_bf16.h>
#include <math.h>

typedef unsigned short ushort_t;
typedef __attribute__((ext_vector_type(8))) short short8;
typedef __attribute__((ext_vector_type(4))) float float4v;
typedef __attribute__((ext_vector_type(16))) float float16v;

#define NN 4096
#define BB 4
#define CC 64
#define ICH 32
#define KSPAN 256  // per-wave split span (16 waves/block)

// workspace (float offsets): QB/KB/VT bf16 + WY + SP = ~7.5 MB
#define OFF_QB 0
#define OFF_KB 262144
#define OFF_VT 524288
#define OFF_WY 786432
#define OFF_SP 1835008

static __device__ __forceinline__ ushort_t f2b(float f) {
  union { float f; unsigned u; } v;
  v.f = f;
  return (ushort_t)((v.u + 0x8000u) >> 16);
}
static __device__ __forceinline__ unsigned pack2(float x, float y) {
  return (unsigned)f2b(x) | ((unsigned)f2b(y) << 16);
}
static __device__ __forceinline__ short8 cvt8lds(const float* p) {
  short8 r;
#pragma unroll
  for (int j = 0; j < 8; j++) r[j] = (short)f2b(p[j]);
  return r;
}

// ---------------------------------------------------------------------------
// Kernel 1: projections via MFMA, one projection per blockIdx.z (proven).
// ---------------------------------------------------------------------------
__global__ __launch_bounds__(256) void proj_kernel(
    const float* __restrict__ xt, const float* __restrict__ xo,
    const float* __restrict__ gw, const float* __restrict__ gb,
    const float* __restrict__ tw, const float* __restrict__ tb,
    const float* __restrict__ pw, const float* __restrict__ pb,
    ushort_t* __restrict__ Qb, ushort_t* __restrict__ Kb,
    ushort_t* __restrict__ Vt) {
  __shared__ float xls[64 * 68];
  __shared__ float wls[ICH * 68];
  __shared__ float bls[ICH];
  __shared__ ushort_t ol[2304];

  int t = threadIdx.x;
  int wv = t >> 6, lane = t & 63, l15 = lane & 15, quad = lane >> 4;
  int b = blockIdx.y, z = blockIdx.z;
  int n0 = blockIdx.x * 64;

  const float* xsrc = (z == 1) ? xo : xt;
  const float* W = (z == 0) ? tw : (z == 1) ? pw : gw;
  const float* Bv = (z == 0) ? tb : (z == 1) ? pb : gb;

#pragma unroll
  for (int it = 0; it < 4; it++) {
    int lin = it * 256 + t;
    int row = lin >> 4, seg = lin & 15;
    float4 v = *(const float4*)(xsrc + ((size_t)(n0 + row) * BB + b) * CC + seg * 4);
    *(float4*)(xls + row * 68 + seg * 4) = v;
  }
#pragma unroll
  for (int it = 0; it < 2; it++) {
    int lin = it * 256 + t;
    int row = lin >> 4, seg = lin & 15;
    float4 v = *(const float4*)(W + (size_t)row * CC + seg * 4);
    *(float4*)(wls + row * 68 + seg * 4) = v;
  }
  if (t < ICH) bls[t] = Bv[t];
  __syncthreads();

  const float* xr = xls + (wv * 16 + l15) * 68;
  short8 a0 = cvt8lds(xr + quad * 8);
  short8 a1 = cvt8lds(xr + 32 + quad * 8);

#pragma unroll
  for (int h = 0; h < 2; h++) {
    int i = h * 16 + l15;
    short8 b0 = cvt8lds(wls + i * 68 + quad * 8);
    short8 b1 = cvt8lds(wls + i * 68 + 32 + quad * 8);
    float bias = bls[i];
    float4v acc = {bias, bias, bias, bias};
    acc = __builtin_amdgcn_mfma_f32_16x16x32_bf16(a0, b0, acc, 0, 0, 0);
    acc = __builtin_amdgcn_mfma_f32_16x16x32_bf16(a1, b1, acc, 0, 0, 0);
    if (z < 2) {
#pragma unroll
      for (int r = 0; r < 4; r++)
        ol[(wv * 16 + quad * 4 + r) * 36 + i] = f2b(acc[r]);
    } else {
#pragma unroll
      for (int r = 0; r < 4; r++)
        ol[i * 68 + wv * 16 + quad * 4 + r] = f2b(acc[r]);
    }
  }
  __syncthreads();

  if (z < 2) {
    ushort_t* dst = (z == 0) ? Kb : Qb;
    int row = t >> 2, seg = t & 3;
    short8 v;
#pragma unroll
    for (int k = 0; k < 8; k++) v[k] = (short)ol[row * 36 + seg * 8 + k];
    *(short8*)(dst + ((size_t)b * NN + n0 + row) * ICH + seg * 8) = v;
  } else {
    int i = t & 31, seg = t >> 5;
    short8 v;
#pragma unroll
    for (int k = 0; k < 8; k++) v[k] = (short)ol[i * 68 + seg * 8 + k];
    *(short8*)(Vt + (size_t)(b * ICH + i) * NN + n0 + seg * 8) = v;
  }
}

// ---------------------------------------------------------------------------
// Kernel 2 (fused): attention + split-combine + wz + BN stat partials.
// Block = 1024 thr = 16 waves; wave w = split w (KSPAN=256, 8 chunks).
// Same total load/VALU work as the R16 512-thread version but 4 waves/SIMD
// instead of 2 (latency hiding).  Combine: waves 0-7 write pot[w], waves
// 8-15 add into pot[w-8] (fixed order, deterministic), then 8-buffer sum.
// ---------------------------------------------------------------------------
__global__ __launch_bounds__(1024) void attn_kernel(
    const ushort_t* __restrict__ Qb, const ushort_t* __restrict__ Kb,
    const ushort_t* __restrict__ Vt, const float* __restrict__ wz_w,
    const float* __restrict__ wz_b, float* __restrict__ WY,
    float* __restrict__ SP) {
  __shared__ float pot[8][ICH][72];  // partial O^T, 8 buffers
  __shared__ float pls[16][64];      // per-wave row-sum partials
  __shared__ float wzl[CC * ICH];
  __shared__ float bls[CC];
  __shared__ float yl[64 * 36];      // y tile [dn][i]
  __shared__ float lsum[64];

  int t = threadIdx.x;
  int w = t >> 6, lane = t & 63;
  int l31 = lane & 31, h = lane >> 5;
  int b = blockIdx.y;
  int q0 = blockIdx.x * 64;
  int blkid = b * 64 + blockIdx.x;

  for (int l = t; l < CC * ICH; l += 1024) wzl[l] = wz_w[l];
  if (t < CC) bls[t] = wz_b[t];

  const ushort_t* Kbb = Kb + (size_t)b * NN * ICH;
  const ushort_t* Vtb = Vt + (size_t)b * ICH * NN;
  int mbeg = w * KSPAN;

  short8 bq0[2], bq1[2];
#pragma unroll
  for (int f = 0; f < 2; f++) {
    const ushort_t* qp = Qb + ((size_t)b * NN + q0 + f * 32 + l31) * ICH + h * 8;
    bq0[f] = *(const short8*)(qp);
    bq1[f] = *(const short8*)(qp + 16);
  }

  float16v ot[2];
#pragma unroll
  for (int f = 0; f < 2; f++)
#pragma unroll
    for (int r = 0; r < 16; r++) ot[f][r] = 0.f;
  float lsp[2] = {0.f, 0.f};

#pragma unroll 2
  for (int c = 0; c < KSPAN / 32; c++) {
    int m0 = mbeg + c * 32;
    const ushort_t* kp = Kbb + (size_t)(m0 + l31) * ICH + h * 8;
    short8 ka0 = *(const short8*)(kp);
    short8 ka1 = *(const short8*)(kp + 16);
    const ushort_t* vp = Vtb + (size_t)l31 * NN + m0 + h * 8;
    short8 va0 = *(const short8*)(vp);
    short8 va1 = *(const short8*)(vp + 16);

#pragma unroll
    for (int f = 0; f < 2; f++) {
      float16v st;
#pragma unroll
      for (int r = 0; r < 16; r++) st[r] = 0.f;
      st = __builtin_amdgcn_mfma_f32_32x32x16_bf16(ka0, bq0[f], st, 0, 0, 0);
      st = __builtin_amdgcn_mfma_f32_32x32x16_bf16(ka1, bq1[f], st, 0, 0, 0);

      float p[16];
#pragma unroll
      for (int r = 0; r < 16; r++) {
        p[r] = __expf(st[r]);
        lsp[f] += p[r];
      }
      unsigned dw[8];
#pragma unroll
      for (int j = 0; j < 8; j++) dw[j] = pack2(p[2 * j], p[2 * j + 1]);

      unsigned send0 = h ? dw[0] : dw[2];
      unsigned send1 = h ? dw[1] : dw[3];
      unsigned r0 = (unsigned)__shfl_xor((int)send0, 32, 64);
      unsigned r1 = (unsigned)__shfl_xor((int)send1, 32, 64);
      union { unsigned u[4]; short8 s8; } b1u;
      b1u.u[0] = h ? r0 : dw[0];
      b1u.u[1] = h ? r1 : dw[1];
      b1u.u[2] = h ? dw[2] : r0;
      b1u.u[3] = h ? dw[3] : r1;
      unsigned send2 = h ? dw[4] : dw[6];
      unsigned send3 = h ? dw[5] : dw[7];
      unsigned r2 = (unsigned)__shfl_xor((int)send2, 32, 64);
      unsigned r3 = (unsigned)__shfl_xor((int)send3, 32, 64);
      union { unsigned u[4]; short8 s8; } b2u;
      b2u.u[0] = h ? r2 : dw[4];
      b2u.u[1] = h ? r3 : dw[5];
      b2u.u[2] = h ? dw[6] : r2;
      b2u.u[3] = h ? dw[7] : r3;

      ot[f] = __builtin_amdgcn_mfma_f32_32x32x16_bf16(va0, b1u.s8, ot[f], 0, 0, 0);
      ot[f] = __builtin_amdgcn_mfma_f32_32x32x16_bf16(va1, b2u.s8, ot[f], 0, 0, 0);
    }
  }

  // per-q row sums (lanes l and l+32 cover complementary kr halves)
  float lv[2];
#pragma unroll
  for (int f = 0; f < 2; f++) {
    float v = lsp[f];
    v += __shfl_xor(v, 32, 64);
    lv[f] = v;
  }

  // two-round deterministic combine into pot[0..7]
  if (w < 8) {
#pragma unroll
    for (int f = 0; f < 2; f++)
#pragma unroll
      for (int r = 0; r < 16; r++) {
        int ch = (r & 3) + 8 * (r >> 2) + 4 * h;
        pot[w][ch][f * 32 + l31] = ot[f][r];
      }
  }
  if (h == 0) {
#pragma unroll
    for (int f = 0; f < 2; f++) pls[w][f * 32 + l31] = lv[f];
  }
  __syncthreads();
  if (w >= 8) {
#pragma unroll
    for (int f = 0; f < 2; f++)
#pragma unroll
      for (int r = 0; r < 16; r++) {
        int ch = (r & 3) + 8 * (r >> 2) + 4 * h;
        pot[w - 8][ch][f * 32 + l31] += ot[f][r];
      }
  }
  __syncthreads();

  if (t < 64) {
    float s = 0.f;
#pragma unroll
    for (int ww = 0; ww < 16; ww++) s += pls[ww][t];
    lsum[t] = s;
  }
  __syncthreads();

  // normalize into yl[dn][i]: 2048 elems over 1024 threads
#pragma unroll
  for (int k = 0; k < 2; k++) {
    int lin = k * 1024 + t;  // 32 i x 64 dn
    int i = lin >> 6, dn = lin & 63;
    float sacc = 0.f;
#pragma unroll
    for (int ww = 0; ww < 8; ww++) sacc += pot[ww][i][dn];
    yl[dn * 36 + i] = sacc / lsum[dn];
  }
  __syncthreads();

  // wz projection + SP partials.  thread -> (c = t>>4, sub = t&15), 4 n each.
  int c = t >> 4, sub = t & 15;
  float4 w4[8];
#pragma unroll
  for (int j = 0; j < 8; j++) w4[j] = ((const float4*)(wzl + c * ICH))[j];
  float bc = bls[c];
  float s1 = 0.f, s2 = 0.f;
#pragma unroll
  for (int d = 0; d < 4; d++) {
    int dn = sub * 4 + d;
    const float4* y4 = (const float4*)(yl + dn * 36);
    float acc = bc;
#pragma unroll
    for (int j = 0; j < 8; j++) {
      float4 y = y4[j];
      acc += w4[j].x * y.x + w4[j].y * y.y + w4[j].z * y.z + w4[j].w * y.w;
    }
    WY[((size_t)(b * CC + c)) * NN + q0 + dn] = acc;
    s1 += acc;
    s2 += acc * acc;
  }
  // reduce over the 16 sub-threads of this c (lanes t^1,2,4,8 within wave)
  s1 += __shfl_xor(s1, 1, 64);
  s2 += __shfl_xor(s2, 1, 64);
  s1 += __shfl_xor(s1, 2, 64);
  s2 += __shfl_xor(s2, 2, 64);
  s1 += __shfl_xor(s1, 4, 64);
  s2 += __shfl_xor(s2, 4, 64);
  s1 += __shfl_xor(s1, 8, 64);
  s2 += __shfl_xor(s2, 8, 64);
  if (sub == 0) {
    SP[(size_t)blkid * 64 + c] = s1;
    SP[16384 + (size_t)blkid * 64 + c] = s2;
  }
}

// ---------------------------------------------------------------------------
// Kernel 3: normalize + residual with per-block final stats (R12-verified).
// ---------------------------------------------------------------------------
__global__ __launch_bounds__(256) void norm_kernel(
    const float* __restrict__ SP, const float* __restrict__ gamma,
    const float* __restrict__ beta, const float* __restrict__ WY,
    const float* __restrict__ xthis, float* __restrict__ out) {
  __shared__ double rd1[256], rd2[256];
  __shared__ float abr[128];
  __shared__ float xl[64 * 65];
  int b = blockIdx.y, n0 = blockIdx.x * 64, t = threadIdx.x;

  {
    int cc = t & 63, part = t >> 6;
    double d1 = 0.0, d2 = 0.0;
    for (int k = part * 64; k < part * 64 + 64; k++) {
      d1 += (double)SP[(size_t)k * 64 + cc];
      d2 += (double)SP[16384 + (size_t)k * 64 + cc];
    }
    rd1[t] = d1;
    rd2[t] = d2;
  }
#pragma unroll
  for (int it = 0; it < 16; it++) {
    int lin = it * 256 + t;
    int c = lin & 63, dn = lin >> 6;
    xl[dn * 65 + c] = xthis[((size_t)(n0 + dn) * BB + b) * CC + c];
  }
  __syncthreads();
  if (t < 64) {
    double a1 = rd1[t] + rd1[64 + t] + rd1[128 + t] + rd1[192 + t];
    double a2 = rd2[t] + rd2[64 + t] + rd2[128 + t] + rd2[192 + t];
    double inv = 1.0 / (double)(BB * NN);
    double mean = a1 * inv;
    double var = a2 * inv - mean * mean;
    if (var < 0.0) var = 0.0;
    double rstd = 1.0 / sqrt(var + 1e-5);
    float A = gamma[t] * (float)rstd;
    abr[t] = A;
    abr[64 + t] = beta[t] - (float)mean * A;
  }
  __syncthreads();
#pragma unroll
  for (int it = 0; it < 16; it++) {
    int lin = it * 256 + t;
    int c = lin >> 6, dn = lin & 63;
    size_t idx = ((size_t)(b * CC + c)) * NN + n0 + dn;
    out[idx] = WY[idx] * abr[c] + abr[64 + c] + xl[dn * 65 + c];
  }
}

// ---------------------------------------------------------------------------
extern "C" void kernel_launch(void* const* d_in, const int* in_sizes, int n_in,
                              void* d_out, int out_size, void* d_ws,
                              size_t ws_size, hipStream_t stream) {
  const float* x_this = (const float*)d_in[0];
  const float* x_other = (const float*)d_in[1];
  const float* g_w = (const float*)d_in[2];
  const float* g_b = (const float*)d_in[3];
  const float* th_w = (const float*)d_in[4];
  const float* th_b = (const float*)d_in[5];
  const float* ph_w = (const float*)d_in[6];
  const float* ph_b = (const float*)d_in[7];
  const float* wz_w = (const float*)d_in[8];
  const float* wz_b = (const float*)d_in[9];
  const float* gamma = (const float*)d_in[10];
  const float* beta = (const float*)d_in[11];
  float* out = (float*)d_out;

  float* ws = (float*)d_ws;
  ushort_t* Qb = (ushort_t*)(ws + OFF_QB);
  ushort_t* Kb = (ushort_t*)(ws + OFF_KB);
  ushort_t* Vt = (ushort_t*)(ws + OFF_VT);
  float* WY = ws + OFF_WY;
  float* SP = ws + OFF_SP;

  hipLaunchKernelGGL(proj_kernel, dim3(NN / 64, BB, 3), dim3(256), 0, stream,
                     x_this, x_other, g_w, g_b, th_w, th_b, ph_w, ph_b,
                     Qb, Kb, Vt);
  hipLaunchKernelGGL(attn_kernel, dim3(NN / 64, BB), dim3(1024), 0, stream,
                     Qb, Kb, Vt, wz_w, wz_b, WY, SP);
  hipLaunchKernelGGL(norm_kernel, dim3(NN / 64, BB), dim3(256), 0, stream,
                     SP, gamma, beta, WY, x_this, out);
}